// Round 1
// baseline (1918.137 us; speedup 1.0000x reference)
//
#include <hip/hip_runtime.h>
#include <math.h>

// HGNNPBlock: per-sample kNN hypergraph (k=30) + 2x (theta -> bn -> v2v mean).
// B=8, L=56*56=3136, C=64, hid=32.
//
// Precision strategy: d2 ranks decide a DISCRETE neighbor set -> compute the
// gram matrix / distances in fp64 (exact fp32->fp64 products) so our top-30
// matches the true (fp64-reference) ordering. Everything post-kNN is smooth
// and runs in fp32 (errors ~1e-6 vs 2% threshold).

namespace {

constexpr int cB = 8;
constexpr int cL = 3136;
constexpr int cC = 64;
constexpr int cH = 32;
constexpr int cK = 30;
constexpr int NV = cB * cL;  // 25088
// float32(1/sqrt(1+1e-5)) — BatchNorm1d eval with running stats (0,1)
constexpr float BN_SC = 0.99999500003749964f;

// ---------------- K0: per-vertex squared norm (fp64) ----------------
__global__ void k_sq(const float* __restrict__ x, double* __restrict__ sq) {
  int v = blockIdx.x * 256 + threadIdx.x;
  if (v >= NV) return;
  const float4* p = reinterpret_cast<const float4*>(x) + (size_t)v * 16;
  double s = 0.0;
#pragma unroll
  for (int i = 0; i < 16; ++i) {
    float4 f = p[i];
    s += (double)f.x * (double)f.x;
    s += (double)f.y * (double)f.y;
    s += (double)f.z * (double)f.z;
    s += (double)f.w * (double)f.w;
  }
  sq[v] = s;
}

// ---------------- K1: fused distance + top-30 selection ----------------
// Per-row max-heap of 30 (d2, idx) in LDS; root = current worst = threshold.
__device__ inline void heap_insert(double* H, int* HI, double v, int idx) {
  if (v >= H[0]) return;  // re-check vs live root (threshold may be stale)
  int pos = 0;
  while (true) {
    int c = 2 * pos + 1;
    if (c >= cK) break;
    double hc = H[c];
    int c2 = c + 1;
    if (c2 < cK) {
      double h2 = H[c2];
      if (h2 > hc) { hc = h2; c = c2; }
    }
    if (hc <= v) break;
    H[pos] = hc; HI[pos] = HI[c]; pos = c;
  }
  H[pos] = v; HI[pos] = idx;
}

// grid = (L/32, B), block = 256 (16x16). Thread (tx,ty) owns rows {ty, ty+16}
// and cols {tx, tx+16, tx+32, tx+48} of the 32x64 d2 tile. Wave w owns rows
// {4w..4w+3} U {4w+16..4w+19} -> heaps are wave-local (no cross-wave sync).
__global__ __launch_bounds__(256) void k_knn(const float* __restrict__ x,
                                             const double* __restrict__ sq,
                                             int* __restrict__ nbr) {
  const int b  = blockIdx.y;
  const int i0 = blockIdx.x * 32;
  const float4* xb  = reinterpret_cast<const float4*>(x) + (size_t)b * cL * 16;
  const double* sqb = sq + (size_t)b * cL;

  __shared__ float4 aS[32 * 17];  // [row][kc], +1 f4 pad: reads are 2-way max
  __shared__ float4 bS[64 * 17];
  __shared__ double hv[32 * cK];
  __shared__ int    hx[32 * cK];
  __shared__ double sqI[32];
  __shared__ double sqJ[64];

  const int t  = threadIdx.x;
  const int tx = t & 15;
  const int ty = t >> 4;

  {  // stage A tile (rows i0..i0+31), coalesced: 16 lanes cover one row
    const int c4 = t & 15, jj = t >> 4;
    aS[jj * 17 + c4]        = xb[(size_t)(i0 + jj) * 16 + c4];
    aS[(jj + 16) * 17 + c4] = xb[(size_t)(i0 + jj + 16) * 16 + c4];
  }
  for (int n = t; n < 32 * cK; n += 256) { hv[n] = 1e300; hx[n] = 0; }
  if (t < 32) sqI[t] = sqb[i0 + t];
  __syncthreads();

  for (int jb = 0; jb < cL; jb += 64) {
    {  // stage B tile
      const int c4 = t & 15, jj = t >> 4;
#pragma unroll
      for (int p = 0; p < 64; p += 16)
        bS[(jj + p) * 17 + c4] = xb[(size_t)(jb + jj + p) * 16 + c4];
      if (t < 64) sqJ[t] = sqb[jb + t];
    }
    __syncthreads();

    double acc[2][4];
#pragma unroll
    for (int i = 0; i < 2; ++i)
#pragma unroll
      for (int q = 0; q < 4; ++q) acc[i][q] = 0.0;

#pragma unroll 4
    for (int kc = 0; kc < 16; ++kc) {
      float4 a0 = aS[ty * 17 + kc];          // broadcast across 16 tx lanes
      float4 a1 = aS[(ty + 16) * 17 + kc];
      float4 b0 = bS[tx * 17 + kc];          // strided cols -> 2-way max
      float4 b1 = bS[(tx + 16) * 17 + kc];
      float4 b2 = bS[(tx + 32) * 17 + kc];
      float4 b3 = bS[(tx + 48) * 17 + kc];
#pragma unroll
      for (int k = 0; k < 4; ++k) {
        double ad0 = (double)((&a0.x)[k]);
        double ad1 = (double)((&a1.x)[k]);
        double bd0 = (double)((&b0.x)[k]);
        double bd1 = (double)((&b1.x)[k]);
        double bd2 = (double)((&b2.x)[k]);
        double bd3 = (double)((&b3.x)[k]);
        acc[0][0] = fma(ad0, bd0, acc[0][0]);
        acc[0][1] = fma(ad0, bd1, acc[0][1]);
        acc[0][2] = fma(ad0, bd2, acc[0][2]);
        acc[0][3] = fma(ad0, bd3, acc[0][3]);
        acc[1][0] = fma(ad1, bd0, acc[1][0]);
        acc[1][1] = fma(ad1, bd1, acc[1][1]);
        acc[1][2] = fma(ad1, bd2, acc[1][2]);
        acc[1][3] = fma(ad1, bd3, acc[1][3]);
      }
    }

    // d2 = |i|^2 + |j|^2 - 2<i,j>; candidate mask vs live heap roots
    double d2v[2][4];
    unsigned pm = 0;
#pragma unroll
    for (int i = 0; i < 2; ++i) {
      const int r = ty + 16 * i;
      const double si   = sqI[r];
      const double root = hv[r * cK];
#pragma unroll
      for (int q = 0; q < 4; ++q) {
        double d2 = si + sqJ[tx + 16 * q] - 2.0 * acc[i][q];
        d2v[i][q] = d2;
        if (d2 < root) pm |= 1u << (i * 4 + q);
      }
    }
    // serialize inserts: step over tx -> at any instant one lane per row
    if (__ballot(pm != 0)) {
      for (int s = 0; s < 16; ++s) {
        if (!__ballot(pm != 0 && tx == s)) continue;
        if (tx == s && pm) {
#pragma unroll
          for (int i = 0; i < 2; ++i) {
            const int r = ty + 16 * i;
#pragma unroll
            for (int q = 0; q < 4; ++q)
              if (pm & (1u << (i * 4 + q)))
                heap_insert(&hv[r * cK], &hx[r * cK], d2v[i][q],
                            jb + tx + 16 * q);
          }
        }
      }
    }
    __syncthreads();  // protect bS/sqJ before next tile's staging
  }

  // dump neighbor sets (order is irrelevant: downstream is mean/segment-sum)
#pragma unroll
  for (int i = 0; i < 2; ++i) {
    const int r = ty + 16 * i;
    int* dst = nbr + ((size_t)b * cL + i0 + r) * cK;
    dst[tx] = hx[r * cK + tx];
    if (tx + 16 < cK) dst[tx + 16] = hx[r * cK + tx + 16];
  }
}

// ---------------- CSR build (vertex -> edges containing it) ----------------
__global__ void k_count(const int* __restrict__ nbr, int* __restrict__ cnt) {
  int g = blockIdx.x * 256 + threadIdx.x;
  if (g >= NV * cK) return;
  int b = g / (cL * cK);
  atomicAdd(&cnt[b * cL + nbr[g]], 1);
}

__global__ void k_scan(const int* __restrict__ cnt, int* __restrict__ rp) {
  int b = blockIdx.x;
  const int* c = cnt + b * cL;
  int* r = rp + b * (cL + 1);
  __shared__ int buf[256];
  int t = threadIdx.x;
  int carry = 0;
  for (int base = 0; base < cL; base += 256) {
    int pos = base + t;
    int v = (pos < cL) ? c[pos] : 0;
    buf[t] = v;
    __syncthreads();
    for (int off = 1; off < 256; off <<= 1) {
      int w = (t >= off) ? buf[t - off] : 0;
      __syncthreads();
      buf[t] += w;
      __syncthreads();
    }
    if (pos < cL) r[pos] = carry + buf[t] - v;  // exclusive prefix
    carry += buf[255];
    __syncthreads();
  }
  if (t == 0) r[cL] = carry;  // == L*K
}

__global__ void k_fill(const int* __restrict__ nbr, const int* __restrict__ rp,
                       int* __restrict__ cur, int* __restrict__ el) {
  int g = blockIdx.x * 256 + threadIdx.x;
  if (g >= NV * cK) return;
  int b = g / (cL * cK);
  int e = (g / cK) % cL;
  int v = nbr[g];
  int p = rp[b * (cL + 1) + v] + atomicAdd(&cur[b * cL + v], 1);
  el[(size_t)b * cL * cK + p] = e;
}

// ---------------- theta + bn (eval) ----------------
__global__ __launch_bounds__(256) void k_theta1(const float* __restrict__ x,
                                                const float* __restrict__ w1,
                                                const float* __restrict__ b1,
                                                const float* __restrict__ g1,
                                                const float* __restrict__ be1,
                                                float* __restrict__ h1) {
  __shared__ float w[cC * cH];
  int t = threadIdx.x;
  for (int n = t; n < cC * cH; n += 256) w[n] = w1[n];
  __syncthreads();
  int g = blockIdx.x * 256 + t;
  int row = g >> 5;
  int f = g & 31;
  const float4* xr = reinterpret_cast<const float4*>(x) + (size_t)row * 16;
  float s = 0.f;
#pragma unroll
  for (int kc = 0; kc < 16; ++kc) {
    float4 xv = xr[kc];
    s += xv.x * w[(4 * kc + 0) * cH + f];
    s += xv.y * w[(4 * kc + 1) * cH + f];
    s += xv.z * w[(4 * kc + 2) * cH + f];
    s += xv.w * w[(4 * kc + 3) * cH + f];
  }
  h1[g] = (s + b1[f]) * (g1[f] * BN_SC) + be1[f];
}

__global__ __launch_bounds__(256) void k_theta2(const float* __restrict__ hin,
                                                const float* __restrict__ w2,
                                                const float* __restrict__ b2,
                                                const float* __restrict__ g2,
                                                const float* __restrict__ be2,
                                                float* __restrict__ h2) {
  __shared__ float w[cH * cC];
  int t = threadIdx.x;
  for (int n = t; n < cH * cC; n += 256) w[n] = w2[n];
  __syncthreads();
  int g = blockIdx.x * 256 + t;
  int row = g >> 6;
  int f = g & 63;
  const float4* hr = reinterpret_cast<const float4*>(hin) + (size_t)row * 8;
  float s = 0.f;
#pragma unroll
  for (int kc = 0; kc < 8; ++kc) {
    float4 hv4 = hr[kc];
    s += hv4.x * w[(4 * kc + 0) * cC + f];
    s += hv4.y * w[(4 * kc + 1) * cC + f];
    s += hv4.z * w[(4 * kc + 2) * cC + f];
    s += hv4.w * w[(4 * kc + 3) * cC + f];
  }
  h2[g] = (s + b2[f]) * (g2[f] * BN_SC) + be2[f];
}

// ---------------- v2e: mean over k neighbors ----------------
template <int F>
__global__ void k_v2e(const float* __restrict__ X, const int* __restrict__ nbr,
                      float* __restrict__ Y) {
  int g = blockIdx.x * 256 + threadIdx.x;
  int er = g / F;  // b*L + e
  int f  = g % F;
  int b  = er / cL;
  const int* nb = nbr + (size_t)er * cK;
  const float* Xb = X + (size_t)b * cL * F;
  float s = 0.f;
#pragma unroll 5
  for (int j = 0; j < cK; ++j) s += Xb[(size_t)nb[j] * F + f];
  Y[g] = s / 30.0f;
}

// ---------------- e2v: mean over incident edges (CSR) ----------------
template <int F, bool RELU>
__global__ void k_e2v(const float* __restrict__ Y, const int* __restrict__ rp,
                      const int* __restrict__ el, float* __restrict__ out) {
  int g = blockIdx.x * 256 + threadIdx.x;
  int vr = g / F;  // b*L + v
  int f  = g % F;
  int b  = vr / cL;
  int v  = vr % cL;
  const int* rpb = rp + b * (cL + 1);
  int s0 = rpb[v], s1 = rpb[v + 1];
  const int* elb = el + (size_t)b * cL * cK;
  const float* Yb = Y + (size_t)b * cL * F;
  float s = 0.f;
  for (int p = s0; p < s1; ++p) s += Yb[(size_t)elb[p] * F + f];
  int deg = s1 - s0;
  if (deg < 1) deg = 1;
  float r = s / (float)deg;
  if (RELU) r = fmaxf(r, 0.f);
  out[g] = r;
}

}  // namespace

extern "C" void kernel_launch(void* const* d_in, const int* in_sizes, int n_in,
                              void* d_out, int out_size, void* d_ws,
                              size_t ws_size, hipStream_t stream) {
  (void)in_sizes; (void)n_in; (void)out_size; (void)ws_size;
  const float* x   = (const float*)d_in[0];
  const float* w1  = (const float*)d_in[1];
  const float* b1  = (const float*)d_in[2];
  const float* g1  = (const float*)d_in[3];
  const float* be1 = (const float*)d_in[4];
  const float* w2  = (const float*)d_in[5];
  const float* b2  = (const float*)d_in[6];
  const float* g2  = (const float*)d_in[7];
  const float* be2 = (const float*)d_in[8];
  float* out = (float*)d_out;

  // workspace partition (~27 MB), 256B aligned
  char* w = (char*)d_ws;
  auto alloc = [&](size_t bytes) {
    char* p = w;
    w += (bytes + 255) & ~size_t(255);
    return p;
  };
  double* sq  = (double*)alloc((size_t)NV * 8);
  int*    cnt = (int*)alloc((size_t)NV * 4);
  int*    cur = (int*)alloc((size_t)NV * 4);
  int*    rp  = (int*)alloc((size_t)cB * (cL + 1) * 4);
  int*    nbr = (int*)alloc((size_t)NV * cK * 4);
  int*    el  = (int*)alloc((size_t)NV * cK * 4);
  float*  h1  = (float*)alloc((size_t)NV * cH * 4);
  float*  Y1  = (float*)alloc((size_t)NV * cH * 4);
  float*  h1v = (float*)alloc((size_t)NV * cH * 4);
  float*  h2  = (float*)alloc((size_t)NV * cC * 4);
  float*  Y2  = (float*)alloc((size_t)NV * cC * 4);

  hipMemsetAsync(cnt, 0, (size_t)NV * 4, stream);
  hipMemsetAsync(cur, 0, (size_t)NV * 4, stream);

  k_sq<<<(NV + 255) / 256, 256, 0, stream>>>(x, sq);
  k_knn<<<dim3(cL / 32, cB), 256, 0, stream>>>(x, sq, nbr);
  k_count<<<(NV * cK + 255) / 256, 256, 0, stream>>>(nbr, cnt);
  k_scan<<<cB, 256, 0, stream>>>(cnt, rp);
  k_fill<<<(NV * cK + 255) / 256, 256, 0, stream>>>(nbr, rp, cur, el);

  k_theta1<<<NV * cH / 256, 256, 0, stream>>>(x, w1, b1, g1, be1, h1);
  k_v2e<cH><<<NV * cH / 256, 256, 0, stream>>>(h1, nbr, Y1);
  k_e2v<cH, true><<<NV * cH / 256, 256, 0, stream>>>(Y1, rp, el, h1v);
  k_theta2<<<NV * cC / 256, 256, 0, stream>>>(h1v, w2, b2, g2, be2, h2);
  k_v2e<cC><<<NV * cC / 256, 256, 0, stream>>>(h2, nbr, Y2);
  k_e2v<cC, false><<<NV * cC / 256, 256, 0, stream>>>(Y2, rp, el, out);
}